// Round 9
// baseline (193.885 us; speedup 1.0000x reference)
//
#include <hip/hip_runtime.h>
#include <hip/hip_fp16.h>

typedef __attribute__((ext_vector_type(8))) _Float16 f16x8;
typedef __attribute__((ext_vector_type(4))) float f32x4;
typedef __attribute__((ext_vector_type(2))) __fp16 fp16x2;

__device__ inline unsigned int pack_f16(float x, float y) {
    union { fp16x2 h; unsigned int u; } c;
    c.h = __builtin_amdgcn_cvt_pkrtz(x, y);
    return c.u;
}
__device__ inline float2 unpack_f16(unsigned int u) {
    union { unsigned int u32; __half2 h2; } c; c.u32 = u;
    return __half22float2(c.h2);
}

// ---------------------------------------------------------------------------
// Kernel 0 (grid 224): bid<128: transpose+cvt W -> WT16[u][d] fp16.
//                      bid 128..191: enc fp32 -> fp16.  192..223: dec -> fp16.
// ---------------------------------------------------------------------------
__global__ __launch_bounds__(256) void prep_w(
    const float* __restrict__ Wenc, const float* __restrict__ Wdec,
    const float* __restrict__ enc,  const float* __restrict__ dec,
    unsigned short* __restrict__ WeT, unsigned short* __restrict__ WdT,
    unsigned short* __restrict__ enc16, unsigned short* __restrict__ dec16)
{
    __shared__ float L[64][65];
    const int bid = blockIdx.x;
    const int t = threadIdx.x;
    if (bid >= 128) {                    // fp32 -> fp16 bulk convert
        const float* src; unsigned int* dst;
        if (bid < 192) { int blk = bid - 128; src = enc + (size_t)blk * 16384;
                         dst = (unsigned int*)enc16 + (size_t)blk * 8192; }
        else           { int blk = bid - 192; src = dec + (size_t)blk * 16384;
                         dst = (unsigned int*)dec16 + (size_t)blk * 8192; }
#pragma unroll 4
        for (int i = 0; i < 16; ++i) {
            int off = (i << 10) + (t << 2);
            float4 v = *(const float4*)(src + off);
            *(uint2*)(dst + (off >> 1)) =
                make_uint2(pack_f16(v.x, v.y), pack_f16(v.z, v.w));
        }
        return;
    }
    const float* W = (bid < 64) ? Wenc : Wdec;
    unsigned short* T = (bid < 64) ? WeT : WdT;
    const int tb = bid & 63;
    const int d0 = (tb >> 3) << 6, u0v = (tb & 7) << 6;
    {
        const int c4 = (t & 15) << 2;
#pragma unroll
        for (int i = 0; i < 4; ++i) {
            int row = (i << 4) + (t >> 4);
            float4 v = *(const float4*)&W[(size_t)(d0 + row) * 512 + u0v + c4];
            L[row][c4 + 0] = v.x;
            L[row][c4 + 1] = v.y;
            L[row][c4 + 2] = v.z;
            L[row][c4 + 3] = v.w;
        }
    }
    __syncthreads();
    const int u = t >> 2, dg = t & 3;
    unsigned int hw[8];
#pragma unroll
    for (int j = 0; j < 8; ++j) {
        float x0 = L[(dg << 4) + (j << 1) + 0][u];
        float x1 = L[(dg << 4) + (j << 1) + 1][u];
        hw[j] = pack_f16(x0, x1);
    }
    size_t ob = (size_t)(u0v + u) * 512 + d0 + (dg << 4);
    *(uint4*)&T[ob]     = make_uint4(hw[0], hw[1], hw[2], hw[3]);
    *(uint4*)&T[ob + 8] = make_uint4(hw[4], hw[5], hw[6], hw[7]);
}

// ---------------------------------------------------------------------------
// Kernel 1 (grid 768, 128 thr = 2 waves): single-pass fp16 MFMA projections.
// All operands fp16, K-contiguous 16B loads; no LDS; 4-deep register pipeline
// (16 K-stages = 4 rounds x 4 stages, branchless wrap).
//   bid<512 : enc proj. Wave tile 32u x 32e (2x2 frags). Epilogue stores
//             E = exp2((d_enc+bias)*2log2e) fp16, u-packed-by-4.
//   bid>=512: dec proj. Wave tile 32q x 32u. Epilogue stores
//             Gt[b][q][u] = exp2((d_dec+bias)*2log2e) fp32.
// ---------------------------------------------------------------------------
__global__ __launch_bounds__(128) void proj_kernel(
    const unsigned short* __restrict__ enc16, const unsigned short* __restrict__ dec16,
    const unsigned short* __restrict__ WeT,   const unsigned short* __restrict__ WdT,
    const float* __restrict__ bias_enc, const float* __restrict__ bias_dec,
    unsigned short* __restrict__ EH,   // [B][128][256][4] fp16
    float* __restrict__ Gt)            // [B][128][512] fp32
{
    const float Cs = 2.8853900817779268f;   // 2*log2(e)
    const int bid = blockIdx.x;
    const int t = threadIdx.x;
    const int lane = t & 63, wx = t >> 6;    // wx: 32-col half
    const int frow = lane & 15, quad = lane >> 4;
    const int ko = quad << 3;

    const unsigned short *pa0, *pa1, *pb0, *pb1;
    if (bid < 512) {
        const int b = bid & 7, s = bid >> 3;
        const int u0 = (s & 15) << 5, e0 = (s >> 4) << 6;
        pa0 = WeT + (size_t)(u0 + frow) * 512 + ko;
        pa1 = pa0 + 16 * 512;
        pb0 = enc16 + (size_t)((b << 8) + e0 + (wx << 5) + frow) * 512 + ko;
        pb1 = pb0 + 16 * 512;
    } else {
        const int s = bid - 512;
        const int b = s & 7, s2 = s >> 3;
        const int q0 = (s2 & 3) << 5, un0 = (s2 >> 2) << 6;
        pa0 = dec16 + (size_t)((b << 7) + q0 + frow) * 512 + ko;
        pa1 = pa0 + 16 * 512;
        pb0 = WdT + (size_t)(un0 + (wx << 5) + frow) * 512 + ko;
        pb1 = pb0 + 16 * 512;
    }

    f16x8 sa[4][2], sb[4][2];
    auto LD = [&](int st, int k) {
        sa[st][0] = *(const f16x8*)(pa0 + k);
        sa[st][1] = *(const f16x8*)(pa1 + k);
        sb[st][0] = *(const f16x8*)(pb0 + k);
        sb[st][1] = *(const f16x8*)(pb1 + k);
    };
    f32x4 acc[2][2] = {{{0.f,0.f,0.f,0.f},{0.f,0.f,0.f,0.f}},
                       {{0.f,0.f,0.f,0.f},{0.f,0.f,0.f,0.f}}};
    LD(0, 0); LD(1, 32); LD(2, 64); LD(3, 96);
    for (int k0 = 0; k0 < 512; k0 += 128) {
#pragma unroll
        for (int st = 0; st < 4; ++st) {
#pragma unroll
            for (int fm = 0; fm < 2; ++fm)
#pragma unroll
                for (int fn = 0; fn < 2; ++fn)
                    acc[fm][fn] = __builtin_amdgcn_mfma_f32_16x16x32_f16(
                        sa[st][fm], sb[st][fn], acc[fm][fn], 0, 0, 0);
            LD(st, (k0 + 128 + (st << 5)) & 511);   // wrapped tail loads harmless
        }
    }

    // epilogue (C/D: col = lane&15, row = quad*4 + reg)
    if (bid < 512) {
        const int b = bid & 7, s = bid >> 3;
        const int u0 = (s & 15) << 5, e0 = (s >> 4) << 6;
#pragma unroll
        for (int fm = 0; fm < 2; ++fm)
#pragma unroll
            for (int fn = 0; fn < 2; ++fn) {
                int ub = u0 + (fm << 4) + (quad << 2);
                int e  = e0 + (wx << 5) + (fn << 4) + frow;
                float4 bi = *(const float4*)&bias_enc[ub];
                float E0 = __builtin_amdgcn_exp2f((acc[fm][fn][0] + bi.x) * Cs);
                float E1 = __builtin_amdgcn_exp2f((acc[fm][fn][1] + bi.y) * Cs);
                float E2 = __builtin_amdgcn_exp2f((acc[fm][fn][2] + bi.z) * Cs);
                float E3 = __builtin_amdgcn_exp2f((acc[fm][fn][3] + bi.w) * Cs);
                ((uint2*)EH)[(((size_t)(b << 7) + (ub >> 2)) << 8) + e] =
                    make_uint2(pack_f16(E0, E1), pack_f16(E2, E3));
            }
    } else {
        const int s = bid - 512;
        const int b = s & 7, s2 = s >> 3;
        const int q0 = (s2 & 3) << 5, un0 = (s2 >> 2) << 6;
#pragma unroll
        for (int fm = 0; fm < 2; ++fm)
#pragma unroll
            for (int fn = 0; fn < 2; ++fn) {
                int qb = q0 + (fm << 4) + (quad << 2);
                int u  = un0 + (wx << 5) + (fn << 4) + frow;
                float bi = bias_dec[u];
#pragma unroll
                for (int g = 0; g < 4; ++g)
                    Gt[(size_t)((b << 7) + qb + g) * 512 + u] =
                        __builtin_amdgcn_exp2f((acc[fm][fn][g] + bi) * Cs);
            }
    }
}

// ---------------------------------------------------------------------------
// Kernel 2 (grid 512, 1024 thr, 2 q per block -> 2 blocks/CU, 32 waves/CU):
// scores s = rcp(1 + E*G) (E precomputed fp16, G fp32) -> softmax -> context.
// 16 waves: 4 e-strips x 4 u-quarters. 4-deep branchless stage rotation.
// ---------------------------------------------------------------------------
__global__ __launch_bounds__(1024) void attend_kernel(
    const unsigned short* __restrict__ enc16,  // [B,256,512] fp16
    const unsigned short* __restrict__ EH,     // [B][128][256][4] fp16
    const float* __restrict__ Gt,              // [B][128][512] fp32
    const float* __restrict__ Wscore,          // [512]
    float* __restrict__ out)                   // [B, 128, 512]
{
    __shared__ float smem[4096];         // accs 8 KB / ctx partials 16 KB
    __shared__ float wT[256][2];         // softmax weights [e][q]

    const float LOG2E = 1.4426950408889634f;

    const int bid = blockIdx.x;
    const int b = bid & 7;               // XCD-local batch
    const int qp = (bid >> 3) & 63;
    const int q0 = qp << 1;
    const int tid = threadIdx.x;
    const int wv = tid >> 6, lane = tid & 63;

    // ---------------- scores ----------------
    const int e  = ((wv & 3) << 6) + lane;
    const int uq = wv >> 2;
    const int u0 = uq << 7;              // 128 u per wave = 32 groups of 4

    const uint2* Ep = (const uint2*)EH + (((size_t)(b << 7) + (u0 >> 2)) << 8) + e;
    const float* G0p = Gt + (size_t)((b << 7) + q0) * 512 + u0;
    const float* G1p = G0p + 512;
    const float* Wp  = Wscore + u0;

    float a0 = 0.f, a1 = 0.f;
    uint2  sE[4];
    float4 sg0[4], sg1[4], sw[4];
    auto LDS_ = [&](int st, int g) {
        sE[st]  = Ep[(size_t)g << 8];
        sg0[st] = *(const float4*)(G0p + (g << 2));
        sg1[st] = *(const float4*)(G1p + (g << 2));
        sw[st]  = *(const float4*)(Wp + (g << 2));
    };
    auto PR = [&](int st) {
        float2 f01 = unpack_f16(sE[st].x);
        float2 f23 = unpack_f16(sE[st].y);
        a0 = fmaf(sw[st].x, __builtin_amdgcn_rcpf(fmaf(f01.x, sg0[st].x, 1.f)), a0);
        a1 = fmaf(sw[st].x, __builtin_amdgcn_rcpf(fmaf(f01.x, sg1[st].x, 1.f)), a1);
        a0 = fmaf(sw[st].y, __builtin_amdgcn_rcpf(fmaf(f01.y, sg0[st].y, 1.f)), a0);
        a1 = fmaf(sw[st].y, __builtin_amdgcn_rcpf(fmaf(f01.y, sg1[st].y, 1.f)), a1);
        a0 = fmaf(sw[st].z, __builtin_amdgcn_rcpf(fmaf(f23.x, sg0[st].z, 1.f)), a0);
        a1 = fmaf(sw[st].z, __builtin_amdgcn_rcpf(fmaf(f23.x, sg1[st].z, 1.f)), a1);
        a0 = fmaf(sw[st].w, __builtin_amdgcn_rcpf(fmaf(f23.y, sg0[st].w, 1.f)), a0);
        a1 = fmaf(sw[st].w, __builtin_amdgcn_rcpf(fmaf(f23.y, sg1[st].w, 1.f)), a1);
    };
    LDS_(0, 0); LDS_(1, 1); LDS_(2, 2); LDS_(3, 3);
    for (int g = 0; g < 32; g += 4) {
#pragma unroll
        for (int st = 0; st < 4; ++st) {
            PR(st);
            LDS_(st, (g + 4 + st) & 31);
        }
    }
    smem[((uq << 1) + 0) * 256 + e] = a0;
    smem[((uq << 1) + 1) * 256 + e] = a1;
    __syncthreads();

    // ---------------- softmax over e per q ----------------
    if (wv < 2) {
        const int q = wv;
        float l[4];
        float m = -1e30f;
#pragma unroll
        for (int i = 0; i < 4; ++i) {
            int ee = lane + (i << 6);
            float a = smem[(0 + q) * 256 + ee] + smem[(2 + q) * 256 + ee] +
                      smem[(4 + q) * 256 + ee] + smem[(6 + q) * 256 + ee];
            l[i] = -2.f * a;
            m = fmaxf(m, l[i]);
        }
#pragma unroll
        for (int mk = 32; mk >= 1; mk >>= 1) m = fmaxf(m, __shfl_xor(m, mk, 64));
        float p[4];
        float ssum = 0.f;
#pragma unroll
        for (int i = 0; i < 4; ++i) {
            p[i] = __builtin_amdgcn_exp2f((l[i] - m) * LOG2E);
            ssum += p[i];
        }
#pragma unroll
        for (int mk = 32; mk >= 1; mk >>= 1) ssum += __shfl_xor(ssum, mk, 64);
        float inv = __builtin_amdgcn_rcpf(ssum);
#pragma unroll
        for (int i = 0; i < 4; ++i) wT[lane + (i << 6)][q] = p[i] * inv;
    }
    __syncthreads();

    // ---------------- context (fp16 enc, 1x read, LDS reduce) ----------------
    {
        const int dp = tid & 255;                // d-pair index
        const int d2 = dp << 1;
        float p0x = 0.f, p0y = 0.f, p1x = 0.f, p1y = 0.f;
        const unsigned int* ep = (const unsigned int*)enc16 +
                                 (((size_t)(b << 8) + (uq << 6)) << 8) + dp;
#pragma unroll 4
        for (int ee = 0; ee < 64; ++ee) {
            float2 x = unpack_f16(ep[(size_t)ee << 8]);
            float2 w2 = *(const float2*)&wT[(uq << 6) + ee][0];  // wave-uniform
            p0x = fmaf(w2.x, x.x, p0x); p0y = fmaf(w2.x, x.y, p0y);
            p1x = fmaf(w2.y, x.x, p1x); p1y = fmaf(w2.y, x.y, p1y);
        }
        float2* sc = (float2*)smem;              // [8][256] float2 = 16 KB
        sc[((uq << 1) + 0) * 256 + dp] = make_float2(p0x, p0y);
        sc[((uq << 1) + 1) * 256 + dp] = make_float2(p1x, p1y);
        __syncthreads();
        if (tid < 512) {
            const int q = tid >> 8, dpf = tid & 255;
            float2 s0 = sc[(0 + q) * 256 + dpf];
            float2 s1 = sc[(2 + q) * 256 + dpf];
            float2 s2 = sc[(4 + q) * 256 + dpf];
            float2 s3 = sc[(6 + q) * 256 + dpf];
            float2 o = make_float2(s0.x + s1.x + s2.x + s3.x,
                                   s0.y + s1.y + s2.y + s3.y);
            *(float2*)&out[(size_t)((b << 7) + q0 + q) * 512 + (dpf << 1)] = o;
        }
    }
}

// ---------------------------------------------------------------------------
extern "C" void kernel_launch(void* const* d_in, const int* in_sizes, int n_in,
                              void* d_out, int out_size, void* d_ws, size_t ws_size,
                              hipStream_t stream) {
    const float* enc      = (const float*)d_in[0];
    const float* dec      = (const float*)d_in[1];
    const float* Wenc     = (const float*)d_in[2];
    const float* Wdec     = (const float*)d_in[3];
    const float* Wscore   = (const float*)d_in[4];
    const float* bias_enc = (const float*)d_in[5];
    const float* bias_dec = (const float*)d_in[6];
    // d_in[7] = bias_score: constant shift, cancelled by softmax.
    float* out = (float*)d_out;

    float* ws = (float*)d_ws;
    unsigned short* EH  = (unsigned short*)ws;             // 2 MB  (1M fp16)
    float* Gt           = ws + 524288;                     // 2 MB  (512K fp32)
    unsigned short* WeT = (unsigned short*)(ws + 1048576); // 512 KB
    unsigned short* WdT = WeT + 262144;                    // 512 KB
    unsigned short* enc16 = WdT + 262144;                  // 2 MB
    unsigned short* dec16 = enc16 + 1048576;               // 1 MB   (total 8 MB)

    prep_w<<<224, 256, 0, stream>>>(Wenc, Wdec, enc, dec, WeT, WdT, enc16, dec16);
    proj_kernel<<<768, 128, 0, stream>>>(enc16, dec16, WeT, WdT,
                                         bias_enc, bias_dec, EH, Gt);
    attend_kernel<<<512, 1024, 0, stream>>>(enc16, EH, Gt, Wscore, out);
}

// Round 10
// 144.918 us; speedup vs baseline: 1.3379x; 1.3379x over previous
//
#include <hip/hip_runtime.h>
#include <hip/hip_fp16.h>

typedef __attribute__((ext_vector_type(8))) _Float16 f16x8;
typedef __attribute__((ext_vector_type(4))) float f32x4;
typedef __attribute__((ext_vector_type(2))) __fp16 fp16x2;

__device__ inline unsigned int pack_f16(float x, float y) {
    union { fp16x2 h; unsigned int u; } c;
    c.h = __builtin_amdgcn_cvt_pkrtz(x, y);
    return c.u;
}
__device__ inline float2 unpack_f16(unsigned int u) {
    union { unsigned int u32; __half2 h2; } c; c.u32 = u;
    return __half22float2(c.h2);
}

// ---------------------------------------------------------------------------
// Kernel 0 (grid 224): bid<128: transpose+cvt W -> WT16[u][d] fp16.
//                      bid 128..191: enc fp32 -> fp16.  192..223: dec -> fp16.
// ---------------------------------------------------------------------------
__global__ __launch_bounds__(256) void prep_w(
    const float* __restrict__ Wenc, const float* __restrict__ Wdec,
    const float* __restrict__ enc,  const float* __restrict__ dec,
    unsigned short* __restrict__ WeT, unsigned short* __restrict__ WdT,
    unsigned short* __restrict__ enc16, unsigned short* __restrict__ dec16)
{
    __shared__ float L[64][65];
    const int bid = blockIdx.x;
    const int t = threadIdx.x;
    if (bid >= 128) {                    // fp32 -> fp16 bulk convert
        const float* src; unsigned int* dst;
        if (bid < 192) { int blk = bid - 128; src = enc + (size_t)blk * 16384;
                         dst = (unsigned int*)enc16 + (size_t)blk * 8192; }
        else           { int blk = bid - 192; src = dec + (size_t)blk * 16384;
                         dst = (unsigned int*)dec16 + (size_t)blk * 8192; }
#pragma unroll 4
        for (int i = 0; i < 16; ++i) {
            int off = (i << 10) + (t << 2);
            float4 v = *(const float4*)(src + off);
            *(uint2*)(dst + (off >> 1)) =
                make_uint2(pack_f16(v.x, v.y), pack_f16(v.z, v.w));
        }
        return;
    }
    const float* W = (bid < 64) ? Wenc : Wdec;
    unsigned short* T = (bid < 64) ? WeT : WdT;
    const int tb = bid & 63;
    const int d0 = (tb >> 3) << 6, u0v = (tb & 7) << 6;
    {
        const int c4 = (t & 15) << 2;
#pragma unroll
        for (int i = 0; i < 4; ++i) {
            int row = (i << 4) + (t >> 4);
            float4 v = *(const float4*)&W[(size_t)(d0 + row) * 512 + u0v + c4];
            L[row][c4 + 0] = v.x;
            L[row][c4 + 1] = v.y;
            L[row][c4 + 2] = v.z;
            L[row][c4 + 3] = v.w;
        }
    }
    __syncthreads();
    const int u = t >> 2, dg = t & 3;
    unsigned int hw[8];
#pragma unroll
    for (int j = 0; j < 8; ++j) {
        float x0 = L[(dg << 4) + (j << 1) + 0][u];
        float x1 = L[(dg << 4) + (j << 1) + 1][u];
        hw[j] = pack_f16(x0, x1);
    }
    size_t ob = (size_t)(u0v + u) * 512 + d0 + (dg << 4);
    *(uint4*)&T[ob]     = make_uint4(hw[0], hw[1], hw[2], hw[3]);
    *(uint4*)&T[ob + 8] = make_uint4(hw[4], hw[5], hw[6], hw[7]);
}

// ---------------------------------------------------------------------------
// Kernel 1 (grid 768, 128 thr = 2 waves): fp16 MFMA projections, no LDS,
// 8-DEEP register pipeline (held in regs: __launch_bounds__(128,1) -> 512-reg
// budget, no spill). Wave = 32x32 tile, full K=512 (16 k-steps).
//   bid<512 : enc proj, rows=u cols=e. Epilogue: E=exp2((d_enc+b)*2log2e)
//             fp16, u-packed-by-4 -> EH.
//   bid>=512: dec proj, rows=q cols=u. Epilogue: Gt[b][q][u]=exp2((dd+b)*C).
// ---------------------------------------------------------------------------
__global__ __launch_bounds__(128, 1) void proj_kernel(
    const unsigned short* __restrict__ enc16, const unsigned short* __restrict__ dec16,
    const unsigned short* __restrict__ WeT,   const unsigned short* __restrict__ WdT,
    const float* __restrict__ bias_enc, const float* __restrict__ bias_dec,
    unsigned short* __restrict__ EH,   // [B][128][256][4] fp16
    float* __restrict__ Gt)            // [B][128][512] fp32
{
    const float Cs = 2.8853900817779268f;   // 2*log2(e)
    const int bid = blockIdx.x;
    const int t = threadIdx.x;
    const int lane = t & 63, wr = t >> 6;    // wr: 32-row half of 64-row tile
    const int frow = lane & 15, quad = lane >> 4;
    const int ko = quad << 3;

    const unsigned short *pa0, *pa1, *pb0, *pb1;
    if (bid < 512) {
        const int b = bid & 7, s = bid >> 3;
        const int u0 = ((s & 7) << 6) + (wr << 5);   // 8 u-tiles of 64
        const int e0 = (s >> 3) << 5;                // 8 e-tiles of 32
        pa0 = WeT + (size_t)(u0 + frow) * 512 + ko;
        pa1 = pa0 + 16 * 512;
        pb0 = enc16 + (size_t)((b << 8) + e0 + frow) * 512 + ko;
        pb1 = pb0 + 16 * 512;
    } else {
        const int s = bid - 512;
        const int b = s & 7, s2 = s >> 3;
        const int q0 = ((s2 >> 4) << 6) + (wr << 5); // 2 q-tiles of 64
        const int u0 = (s2 & 15) << 5;               // 16 u-tiles of 32
        pa0 = dec16 + (size_t)((b << 7) + q0 + frow) * 512 + ko;
        pa1 = pa0 + 16 * 512;
        pb0 = WdT + (size_t)(u0 + frow) * 512 + ko;
        pb1 = pb0 + 16 * 512;
    }

    f16x8 sa0[8], sa1[8], sb0[8], sb1[8];
    auto LD = [&](int st, int k) {
        sa0[st] = *(const f16x8*)(pa0 + k);
        sa1[st] = *(const f16x8*)(pa1 + k);
        sb0[st] = *(const f16x8*)(pb0 + k);
        sb1[st] = *(const f16x8*)(pb1 + k);
    };
    f32x4 acc[2][2] = {{{0.f,0.f,0.f,0.f},{0.f,0.f,0.f,0.f}},
                       {{0.f,0.f,0.f,0.f},{0.f,0.f,0.f,0.f}}};
#pragma unroll
    for (int st = 0; st < 8; ++st) LD(st, st << 5);
    for (int k0 = 0; k0 < 512; k0 += 256) {
#pragma unroll
        for (int st = 0; st < 8; ++st) {
            acc[0][0] = __builtin_amdgcn_mfma_f32_16x16x32_f16(sa0[st], sb0[st], acc[0][0], 0, 0, 0);
            acc[0][1] = __builtin_amdgcn_mfma_f32_16x16x32_f16(sa0[st], sb1[st], acc[0][1], 0, 0, 0);
            acc[1][0] = __builtin_amdgcn_mfma_f32_16x16x32_f16(sa1[st], sb0[st], acc[1][0], 0, 0, 0);
            acc[1][1] = __builtin_amdgcn_mfma_f32_16x16x32_f16(sa1[st], sb1[st], acc[1][1], 0, 0, 0);
            LD(st, (k0 + 256 + (st << 5)) & 511);   // wrapped tail reload harmless
        }
    }

    // epilogue (C/D: col = lane&15 -> B-row, row = quad*4 + reg -> A-row)
    if (bid < 512) {
        const int b = bid & 7, s = bid >> 3;
        const int u0 = ((s & 7) << 6) + (wr << 5);
        const int e0 = (s >> 3) << 5;
#pragma unroll
        for (int fm = 0; fm < 2; ++fm)
#pragma unroll
            for (int fn = 0; fn < 2; ++fn) {
                int ub = u0 + (fm << 4) + (quad << 2);
                int e  = e0 + (fn << 4) + frow;
                float4 bi = *(const float4*)&bias_enc[ub];
                float E0 = __builtin_amdgcn_exp2f((acc[fm][fn][0] + bi.x) * Cs);
                float E1 = __builtin_amdgcn_exp2f((acc[fm][fn][1] + bi.y) * Cs);
                float E2 = __builtin_amdgcn_exp2f((acc[fm][fn][2] + bi.z) * Cs);
                float E3 = __builtin_amdgcn_exp2f((acc[fm][fn][3] + bi.w) * Cs);
                ((uint2*)EH)[(((size_t)(b << 7) + (ub >> 2)) << 8) + e] =
                    make_uint2(pack_f16(E0, E1), pack_f16(E2, E3));
            }
    } else {
        const int s = bid - 512;
        const int b = s & 7, s2 = s >> 3;
        const int q0 = ((s2 >> 4) << 6) + (wr << 5);
        const int u0 = (s2 & 15) << 5;
#pragma unroll
        for (int fm = 0; fm < 2; ++fm)
#pragma unroll
            for (int fn = 0; fn < 2; ++fn) {
                int qb = q0 + (fm << 4) + (quad << 2);
                int u  = u0 + (fn << 4) + frow;
                float bi = bias_dec[u];
#pragma unroll
                for (int g = 0; g < 4; ++g)
                    Gt[(size_t)((b << 7) + qb + g) * 512 + u] =
                        __builtin_amdgcn_exp2f((acc[fm][fn][g] + bi) * Cs);
            }
    }
}

// ---------------------------------------------------------------------------
// Kernel 2 (grid 512 x 1024 thr, 2 q/block -> 2 blocks/CU = 32 waves/CU):
// scores s = rcp(1 + E*G) (E fp16 precomputed, G fp32) -> softmax -> context.
// __launch_bounds__(1024,8): 64-reg cap; 2-deep 14-reg stages (no spill).
// 16 waves: 4 e-strips x 4 u-quarters.
// ---------------------------------------------------------------------------
__global__ __launch_bounds__(1024, 8) void attend_kernel(
    const unsigned short* __restrict__ enc16,  // [B,256,512] fp16
    const unsigned short* __restrict__ EH,     // [B][128][256][4] fp16
    const float* __restrict__ Gt,              // [B][128][512] fp32
    const float* __restrict__ Wscore,          // [512]
    float* __restrict__ out)                   // [B, 128, 512]
{
    __shared__ float smem[4096];         // accs 8 KB / ctx partials 16 KB
    __shared__ float wT[256][2];         // softmax weights [e][q]

    const float LOG2E = 1.4426950408889634f;

    const int bid = blockIdx.x;
    const int b = bid & 7;               // XCD-local batch
    const int q0 = ((bid >> 3) & 63) << 1;
    const int tid = threadIdx.x;
    const int wv = tid >> 6, lane = tid & 63;

    // ---------------- scores ----------------
    const int e  = ((wv & 3) << 6) + lane;
    const int uq = wv >> 2;
    const int u0 = uq << 7;              // 128 u per wave = 32 groups of 4

    const uint2* Ep = (const uint2*)EH + (((size_t)(b << 7) + (u0 >> 2)) << 8) + e;
    const float* G0p = Gt + (size_t)((b << 7) + q0) * 512 + u0;
    const float* G1p = G0p + 512;
    const float* Wp  = Wscore + u0;

    float a0 = 0.f, a1 = 0.f;
    uint2  sE[2];
    float4 sg0[2], sg1[2], sw[2];
    auto LDS_ = [&](int st, int g) {
        sE[st]  = Ep[(size_t)g << 8];
        sg0[st] = *(const float4*)(G0p + (g << 2));
        sg1[st] = *(const float4*)(G1p + (g << 2));
        sw[st]  = *(const float4*)(Wp + (g << 2));
    };
    auto PR = [&](int st) {
        float2 f01 = unpack_f16(sE[st].x);
        float2 f23 = unpack_f16(sE[st].y);
        a0 = fmaf(sw[st].x, __builtin_amdgcn_rcpf(fmaf(f01.x, sg0[st].x, 1.f)), a0);
        a1 = fmaf(sw[st].x, __builtin_amdgcn_rcpf(fmaf(f01.x, sg1[st].x, 1.f)), a1);
        a0 = fmaf(sw[st].y, __builtin_amdgcn_rcpf(fmaf(f01.y, sg0[st].y, 1.f)), a0);
        a1 = fmaf(sw[st].y, __builtin_amdgcn_rcpf(fmaf(f01.y, sg1[st].y, 1.f)), a1);
        a0 = fmaf(sw[st].z, __builtin_amdgcn_rcpf(fmaf(f23.x, sg0[st].z, 1.f)), a0);
        a1 = fmaf(sw[st].z, __builtin_amdgcn_rcpf(fmaf(f23.x, sg1[st].z, 1.f)), a1);
        a0 = fmaf(sw[st].w, __builtin_amdgcn_rcpf(fmaf(f23.y, sg0[st].w, 1.f)), a0);
        a1 = fmaf(sw[st].w, __builtin_amdgcn_rcpf(fmaf(f23.y, sg1[st].w, 1.f)), a1);
    };
    LDS_(0, 0); LDS_(1, 1);
    for (int g = 0; g < 32; g += 2) {
        PR(0); LDS_(0, (g + 2) & 31);
        PR(1); LDS_(1, (g + 3) & 31);
    }
    smem[((uq << 1) + 0) * 256 + e] = a0;
    smem[((uq << 1) + 1) * 256 + e] = a1;
    __syncthreads();

    // ---------------- softmax over e per q ----------------
    if (wv < 2) {
        const int q = wv;
        float l[4];
        float m = -1e30f;
#pragma unroll
        for (int i = 0; i < 4; ++i) {
            int ee = lane + (i << 6);
            float a = smem[(0 + q) * 256 + ee] + smem[(2 + q) * 256 + ee] +
                      smem[(4 + q) * 256 + ee] + smem[(6 + q) * 256 + ee];
            l[i] = -2.f * a;
            m = fmaxf(m, l[i]);
        }
#pragma unroll
        for (int mk = 32; mk >= 1; mk >>= 1) m = fmaxf(m, __shfl_xor(m, mk, 64));
        float p[4];
        float ssum = 0.f;
#pragma unroll
        for (int i = 0; i < 4; ++i) {
            p[i] = __builtin_amdgcn_exp2f((l[i] - m) * LOG2E);
            ssum += p[i];
        }
#pragma unroll
        for (int mk = 32; mk >= 1; mk >>= 1) ssum += __shfl_xor(ssum, mk, 64);
        float inv = __builtin_amdgcn_rcpf(ssum);
#pragma unroll
        for (int i = 0; i < 4; ++i) wT[lane + (i << 6)][q] = p[i] * inv;
    }
    __syncthreads();

    // ---------------- context (fp16 enc, 1x read, LDS reduce) ----------------
    {
        const int dp = tid & 255;                // d-pair index
        float p0x = 0.f, p0y = 0.f, p1x = 0.f, p1y = 0.f;
        const unsigned int* ep = (const unsigned int*)enc16 +
                                 (((size_t)(b << 8) + (uq << 6)) << 8) + dp;
#pragma unroll 4
        for (int ee = 0; ee < 64; ++ee) {
            float2 x = unpack_f16(ep[(size_t)ee << 8]);
            float2 w2 = *(const float2*)&wT[(uq << 6) + ee][0];  // wave-uniform
            p0x = fmaf(w2.x, x.x, p0x); p0y = fmaf(w2.x, x.y, p0y);
            p1x = fmaf(w2.y, x.x, p1x); p1y = fmaf(w2.y, x.y, p1y);
        }
        float2* sc = (float2*)smem;              // [8][256] float2 = 16 KB
        sc[((uq << 1) + 0) * 256 + dp] = make_float2(p0x, p0y);
        sc[((uq << 1) + 1) * 256 + dp] = make_float2(p1x, p1y);
        __syncthreads();
        if (tid < 512) {
            const int q = tid >> 8, dpf = tid & 255;
            float2 s0 = sc[(0 + q) * 256 + dpf];
            float2 s1 = sc[(2 + q) * 256 + dpf];
            float2 s2 = sc[(4 + q) * 256 + dpf];
            float2 s3 = sc[(6 + q) * 256 + dpf];
            float2 o = make_float2(s0.x + s1.x + s2.x + s3.x,
                                   s0.y + s1.y + s2.y + s3.y);
            *(float2*)&out[(size_t)((b << 7) + q0 + q) * 512 + (dpf << 1)] = o;
        }
    }
}

// ---------------------------------------------------------------------------
extern "C" void kernel_launch(void* const* d_in, const int* in_sizes, int n_in,
                              void* d_out, int out_size, void* d_ws, size_t ws_size,
                              hipStream_t stream) {
    const float* enc      = (const float*)d_in[0];
    const float* dec      = (const float*)d_in[1];
    const float* Wenc     = (const float*)d_in[2];
    const float* Wdec     = (const float*)d_in[3];
    const float* Wscore   = (const float*)d_in[4];
    const float* bias_enc = (const float*)d_in[5];
    const float* bias_dec = (const float*)d_in[6];
    // d_in[7] = bias_score: constant shift, cancelled by softmax.
    float* out = (float*)d_out;

    float* ws = (float*)d_ws;
    unsigned short* EH  = (unsigned short*)ws;             // 2 MB  (1M fp16)
    float* Gt           = ws + 524288;                     // 2 MB  (512K fp32)
    unsigned short* WeT = (unsigned short*)(ws + 1048576); // 512 KB
    unsigned short* WdT = WeT + 262144;                    // 512 KB
    unsigned short* enc16 = WdT + 262144;                  // 2 MB
    unsigned short* dec16 = enc16 + 1048576;               // 1 MB   (total 8 MB)

    prep_w<<<224, 256, 0, stream>>>(Wenc, Wdec, enc, dec, WeT, WdT, enc16, dec16);
    proj_kernel<<<768, 128, 0, stream>>>(enc16, dec16, WeT, WdT,
                                         bias_enc, bias_dec, EH, Gt);
    attend_kernel<<<512, 1024, 0, stream>>>(enc16, EH, Gt, Wscore, out);
}

// Round 11
// 110.048 us; speedup vs baseline: 1.7618x; 1.3169x over previous
//
#include <hip/hip_runtime.h>
#include <hip/hip_fp16.h>

typedef __attribute__((ext_vector_type(8))) _Float16 f16x8;
typedef __attribute__((ext_vector_type(4))) float f32x4;
typedef __attribute__((ext_vector_type(2))) __fp16 fp16x2;

__device__ inline unsigned int pack_f16(float x, float y) {
    union { fp16x2 h; unsigned int u; } c;
    c.h = __builtin_amdgcn_cvt_pkrtz(x, y);
    return c.u;
}
__device__ inline float2 unpack_f16(unsigned int u) {
    union { unsigned int u32; __half2 h2; } c; c.u32 = u;
    return __half22float2(c.h2);
}

// ---------------------------------------------------------------------------
// Kernel 0 (grid 224): bid<128: transpose+cvt W -> WT16[u][d] fp16.
//                      bid 128..191: enc fp32 -> fp16.  192..223: dec -> fp16.
// ---------------------------------------------------------------------------
__global__ __launch_bounds__(256) void prep_w(
    const float* __restrict__ Wenc, const float* __restrict__ Wdec,
    const float* __restrict__ enc,  const float* __restrict__ dec,
    unsigned short* __restrict__ WeT, unsigned short* __restrict__ WdT,
    unsigned short* __restrict__ enc16, unsigned short* __restrict__ dec16)
{
    __shared__ float L[64][65];
    const int bid = blockIdx.x;
    const int t = threadIdx.x;
    if (bid >= 128) {                    // fp32 -> fp16 bulk convert
        const float* src; unsigned int* dst;
        if (bid < 192) { int blk = bid - 128; src = enc + (size_t)blk * 16384;
                         dst = (unsigned int*)enc16 + (size_t)blk * 8192; }
        else           { int blk = bid - 192; src = dec + (size_t)blk * 16384;
                         dst = (unsigned int*)dec16 + (size_t)blk * 8192; }
#pragma unroll 4
        for (int i = 0; i < 16; ++i) {
            int off = (i << 10) + (t << 2);
            float4 v = *(const float4*)(src + off);
            *(uint2*)(dst + (off >> 1)) =
                make_uint2(pack_f16(v.x, v.y), pack_f16(v.z, v.w));
        }
        return;
    }
    const float* W = (bid < 64) ? Wenc : Wdec;
    unsigned short* T = (bid < 64) ? WeT : WdT;
    const int tb = bid & 63;
    const int d0 = (tb >> 3) << 6, u0v = (tb & 7) << 6;
    {
        const int c4 = (t & 15) << 2;
#pragma unroll
        for (int i = 0; i < 4; ++i) {
            int row = (i << 4) + (t >> 4);
            float4 v = *(const float4*)&W[(size_t)(d0 + row) * 512 + u0v + c4];
            L[row][c4 + 0] = v.x;
            L[row][c4 + 1] = v.y;
            L[row][c4 + 2] = v.z;
            L[row][c4 + 3] = v.w;
        }
    }
    __syncthreads();
    const int u = t >> 2, dg = t & 3;
    unsigned int hw[8];
#pragma unroll
    for (int j = 0; j < 8; ++j) {
        float x0 = L[(dg << 4) + (j << 1) + 0][u];
        float x1 = L[(dg << 4) + (j << 1) + 1][u];
        hw[j] = pack_f16(x0, x1);
    }
    size_t ob = (size_t)(u0v + u) * 512 + d0 + (dg << 4);
    *(uint4*)&T[ob]     = make_uint4(hw[0], hw[1], hw[2], hw[3]);
    *(uint4*)&T[ob + 8] = make_uint4(hw[4], hw[5], hw[6], hw[7]);
}

// ---------------------------------------------------------------------------
// Kernel 1 (grid 768, 128 thr = 2 waves): fp16 MFMA projections, no LDS,
// 4-deep register pipeline (64 stage VGPRs -> no spill under (128,1)).
//   bid<512 : enc proj, rows=u cols=e. Epilogue: EH = exp2((d_enc+b)*2log2e)
//             fp16, u-packed-by-4.
//   bid>=512: dec proj, rows=q cols=u. Epilogue:
//             Gq4[b][q>>2][u][q&3] = exp2((dd+b)*2log2e) fp32 (q-packed).
// ---------------------------------------------------------------------------
__global__ __launch_bounds__(128, 1) void proj_kernel(
    const unsigned short* __restrict__ enc16, const unsigned short* __restrict__ dec16,
    const unsigned short* __restrict__ WeT,   const unsigned short* __restrict__ WdT,
    const float* __restrict__ bias_enc, const float* __restrict__ bias_dec,
    unsigned short* __restrict__ EH,   // [B][128][256][4] fp16
    float* __restrict__ Gq4)           // [B][32][512][4] fp32
{
    const float Cs = 2.8853900817779268f;   // 2*log2(e)
    const int bid = blockIdx.x;
    const int t = threadIdx.x;
    const int lane = t & 63, wr = t >> 6;    // wr: 32-row half of 64-row tile
    const int frow = lane & 15, quad = lane >> 4;
    const int ko = quad << 3;

    const unsigned short *pa0, *pa1, *pb0, *pb1;
    if (bid < 512) {
        const int b = bid & 7, s = bid >> 3;
        const int u0 = ((s & 7) << 6) + (wr << 5);   // 8 u-tiles of 64
        const int e0 = (s >> 3) << 5;                // 8 e-tiles of 32
        pa0 = WeT + (size_t)(u0 + frow) * 512 + ko;
        pa1 = pa0 + 16 * 512;
        pb0 = enc16 + (size_t)((b << 8) + e0 + frow) * 512 + ko;
        pb1 = pb0 + 16 * 512;
    } else {
        const int s = bid - 512;
        const int b = s & 7, s2 = s >> 3;
        const int q0 = ((s2 >> 4) << 6) + (wr << 5); // 2 q-tiles of 64
        const int u0 = (s2 & 15) << 5;               // 16 u-tiles of 32
        pa0 = dec16 + (size_t)((b << 7) + q0 + frow) * 512 + ko;
        pa1 = pa0 + 16 * 512;
        pb0 = WdT + (size_t)(u0 + frow) * 512 + ko;
        pb1 = pb0 + 16 * 512;
    }

    f16x8 sa0[4], sa1[4], sb0[4], sb1[4];
    auto LD = [&](int st, int k) {
        sa0[st] = *(const f16x8*)(pa0 + k);
        sa1[st] = *(const f16x8*)(pa1 + k);
        sb0[st] = *(const f16x8*)(pb0 + k);
        sb1[st] = *(const f16x8*)(pb1 + k);
    };
    f32x4 acc[2][2] = {{{0.f,0.f,0.f,0.f},{0.f,0.f,0.f,0.f}},
                       {{0.f,0.f,0.f,0.f},{0.f,0.f,0.f,0.f}}};
    LD(0, 0); LD(1, 32); LD(2, 64); LD(3, 96);
    for (int k0 = 0; k0 < 512; k0 += 128) {
#pragma unroll
        for (int st = 0; st < 4; ++st) {
            acc[0][0] = __builtin_amdgcn_mfma_f32_16x16x32_f16(sa0[st], sb0[st], acc[0][0], 0, 0, 0);
            acc[0][1] = __builtin_amdgcn_mfma_f32_16x16x32_f16(sa0[st], sb1[st], acc[0][1], 0, 0, 0);
            acc[1][0] = __builtin_amdgcn_mfma_f32_16x16x32_f16(sa1[st], sb0[st], acc[1][0], 0, 0, 0);
            acc[1][1] = __builtin_amdgcn_mfma_f32_16x16x32_f16(sa1[st], sb1[st], acc[1][1], 0, 0, 0);
            LD(st, (k0 + 128 + (st << 5)) & 511);   // wrapped tail reload harmless
        }
    }

    // epilogue (C/D: col = lane&15 -> B-row, row = quad*4 + reg -> A-row)
    if (bid < 512) {
        const int b = bid & 7, s = bid >> 3;
        const int u0 = ((s & 7) << 6) + (wr << 5);
        const int e0 = (s >> 3) << 5;
#pragma unroll
        for (int fm = 0; fm < 2; ++fm)
#pragma unroll
            for (int fn = 0; fn < 2; ++fn) {
                int ub = u0 + (fm << 4) + (quad << 2);
                int e  = e0 + (fn << 4) + frow;
                float4 bi = *(const float4*)&bias_enc[ub];
                float E0 = __builtin_amdgcn_exp2f((acc[fm][fn][0] + bi.x) * Cs);
                float E1 = __builtin_amdgcn_exp2f((acc[fm][fn][1] + bi.y) * Cs);
                float E2 = __builtin_amdgcn_exp2f((acc[fm][fn][2] + bi.z) * Cs);
                float E3 = __builtin_amdgcn_exp2f((acc[fm][fn][3] + bi.w) * Cs);
                ((uint2*)EH)[(((size_t)(b << 7) + (ub >> 2)) << 8) + e] =
                    make_uint2(pack_f16(E0, E1), pack_f16(E2, E3));
            }
    } else {
        const int s = bid - 512;
        const int b = s & 7, s2 = s >> 3;
        const int q0 = ((s2 >> 4) << 6) + (wr << 5);
        const int u0 = (s2 & 15) << 5;
#pragma unroll
        for (int fm = 0; fm < 2; ++fm)
#pragma unroll
            for (int fn = 0; fn < 2; ++fn) {
                int qb = q0 + (fm << 4) + (quad << 2);   // multiple of 4
                int u  = u0 + (fn << 4) + frow;
                float bi = bias_dec[u];
                size_t base = (((size_t)(b << 5) + (qb >> 2)) << 11) + (u << 2);
#pragma unroll
                for (int g = 0; g < 4; ++g)
                    Gq4[base + g] =
                        __builtin_amdgcn_exp2f((acc[fm][fn][g] + bi) * Cs);
            }
    }
}

// ---------------------------------------------------------------------------
// Kernel 2 (grid 256, 1024 thr, q=4/block): scores -> softmax -> context.
// Score loop (R6 structure): E fp16 8B vector load; G (q-packed, 64B) and
// Wscore (16B) via readfirstlane-pinned SCALAR loads (s_load path);
// 1-deep prefetch. s = rcp(1 + E*G); logits = -2*sum (consts cancel).
// __launch_bounds__(1024,4): 128-reg cap, no spill.
// ---------------------------------------------------------------------------
__global__ __launch_bounds__(1024, 4) void attend_kernel(
    const unsigned short* __restrict__ enc16,  // [B,256,512] fp16
    const unsigned short* __restrict__ EH,     // [B][128][256][4] fp16
    const float* __restrict__ Gq4,             // [B][32][512][4] fp32
    const float* __restrict__ Wscore,          // [512]
    float* __restrict__ out)                   // [B, 128, 512]
{
    __shared__ float smem[8192];         // score accs 16 KB / ctx partials 32 KB
    __shared__ float wT[256][4];         // softmax weights [e][q]

    const float LOG2E = 1.4426950408889634f;

    const int bid = blockIdx.x;
    const int b = bid & 7;               // XCD-local batch
    const int qt = (bid >> 3) & 31;
    const int q0 = qt << 2;
    const int tid = threadIdx.x;
    const int wv = tid >> 6, lane = tid & 63;

    // ---------------- scores ----------------
    const int e  = ((wv & 3) << 6) + lane;
    const int uq = wv >> 2;
    const int u0 = __builtin_amdgcn_readfirstlane(uq << 7);   // SGPR-pinned

    const uint2* Ep = (const uint2*)EH + (((size_t)(b << 7) + (u0 >> 2)) << 8) + e;
    const float* Gq = Gq4 + (((size_t)(b << 5) + qt) << 11);  // [512][4]
    const float* Wp = Wscore + u0;

    float a0 = 0.f, a1 = 0.f, a2 = 0.f, a3 = 0.f;
    uint2 de = Ep[0];
    float4 g0 = *(const float4*)(Gq + ((u0 + 0) << 2));
    float4 g1 = *(const float4*)(Gq + ((u0 + 1) << 2));
    float4 g2 = *(const float4*)(Gq + ((u0 + 2) << 2));
    float4 g3 = *(const float4*)(Gq + ((u0 + 3) << 2));
    float4 w4 = *(const float4*)(Wp);
    for (int g = 0; g < 32; ++g) {
        uint2 cde = de;
        float4 cg0 = g0, cg1 = g1, cg2 = g2, cg3 = g3, cw = w4;
        if (g < 31) {
            int un = u0 + ((g + 1) << 2);
            de = Ep[(size_t)(g + 1) << 8];
            g0 = *(const float4*)(Gq + ((un + 0) << 2));
            g1 = *(const float4*)(Gq + ((un + 1) << 2));
            g2 = *(const float4*)(Gq + ((un + 2) << 2));
            g3 = *(const float4*)(Gq + ((un + 3) << 2));
            w4 = *(const float4*)(Wp + (g + 1 - g/32) * 0 + ((g + 1) << 2));
        }
        float2 f01 = unpack_f16(cde.x);
        float2 f23 = unpack_f16(cde.y);
        float E;
        E = f01.x;
        a0 = fmaf(cw.x, __builtin_amdgcn_rcpf(fmaf(E, cg0.x, 1.f)), a0);
        a1 = fmaf(cw.x, __builtin_amdgcn_rcpf(fmaf(E, cg0.y, 1.f)), a1);
        a2 = fmaf(cw.x, __builtin_amdgcn_rcpf(fmaf(E, cg0.z, 1.f)), a2);
        a3 = fmaf(cw.x, __builtin_amdgcn_rcpf(fmaf(E, cg0.w, 1.f)), a3);
        E = f01.y;
        a0 = fmaf(cw.y, __builtin_amdgcn_rcpf(fmaf(E, cg1.x, 1.f)), a0);
        a1 = fmaf(cw.y, __builtin_amdgcn_rcpf(fmaf(E, cg1.y, 1.f)), a1);
        a2 = fmaf(cw.y, __builtin_amdgcn_rcpf(fmaf(E, cg1.z, 1.f)), a2);
        a3 = fmaf(cw.y, __builtin_amdgcn_rcpf(fmaf(E, cg1.w, 1.f)), a3);
        E = f23.x;
        a0 = fmaf(cw.z, __builtin_amdgcn_rcpf(fmaf(E, cg2.x, 1.f)), a0);
        a1 = fmaf(cw.z, __builtin_amdgcn_rcpf(fmaf(E, cg2.y, 1.f)), a1);
        a2 = fmaf(cw.z, __builtin_amdgcn_rcpf(fmaf(E, cg2.z, 1.f)), a2);
        a3 = fmaf(cw.z, __builtin_amdgcn_rcpf(fmaf(E, cg2.w, 1.f)), a3);
        E = f23.y;
        a0 = fmaf(cw.w, __builtin_amdgcn_rcpf(fmaf(E, cg3.x, 1.f)), a0);
        a1 = fmaf(cw.w, __builtin_amdgcn_rcpf(fmaf(E, cg3.y, 1.f)), a1);
        a2 = fmaf(cw.w, __builtin_amdgcn_rcpf(fmaf(E, cg3.z, 1.f)), a2);
        a3 = fmaf(cw.w, __builtin_amdgcn_rcpf(fmaf(E, cg3.w, 1.f)), a3);
    }
    smem[((uq << 2) + 0) * 256 + e] = a0;
    smem[((uq << 2) + 1) * 256 + e] = a1;
    smem[((uq << 2) + 2) * 256 + e] = a2;
    smem[((uq << 2) + 3) * 256 + e] = a3;
    __syncthreads();

    // ---------------- softmax over e per q ----------------
    if (wv < 4) {
        const int q = wv;
        float l[4];
        float m = -1e30f;
#pragma unroll
        for (int i = 0; i < 4; ++i) {
            int ee = lane + (i << 6);
            float a = smem[(0 + q) * 256 + ee] + smem[(4 + q) * 256 + ee] +
                      smem[(8 + q) * 256 + ee] + smem[(12 + q) * 256 + ee];
            l[i] = -2.f * a;
            m = fmaxf(m, l[i]);
        }
#pragma unroll
        for (int mk = 32; mk >= 1; mk >>= 1) m = fmaxf(m, __shfl_xor(m, mk, 64));
        float p[4];
        float ssum = 0.f;
#pragma unroll
        for (int i = 0; i < 4; ++i) {
            p[i] = __builtin_amdgcn_exp2f((l[i] - m) * LOG2E);
            ssum += p[i];
        }
#pragma unroll
        for (int mk = 32; mk >= 1; mk >>= 1) ssum += __shfl_xor(ssum, mk, 64);
        float inv = __builtin_amdgcn_rcpf(ssum);
#pragma unroll
        for (int i = 0; i < 4; ++i) wT[lane + (i << 6)][q] = p[i] * inv;
    }
    __syncthreads();

    // ---------------- context (fp16 enc, 1x read, LDS reduce) ----------------
    {
        const int dp = tid & 255;                // d-pair index
        float p0x = 0.f, p0y = 0.f, p1x = 0.f, p1y = 0.f;
        float p2x = 0.f, p2y = 0.f, p3x = 0.f, p3y = 0.f;
        const unsigned int* ep = (const unsigned int*)enc16 +
                                 (((size_t)(b << 8) + (uq << 6)) << 8) + dp;
#pragma unroll 4
        for (int ee = 0; ee < 64; ++ee) {
            float2 x = unpack_f16(ep[(size_t)ee << 8]);
            float4 w = *(const float4*)&wT[(uq << 6) + ee][0];   // wave-uniform
            p0x = fmaf(w.x, x.x, p0x); p0y = fmaf(w.x, x.y, p0y);
            p1x = fmaf(w.y, x.x, p1x); p1y = fmaf(w.y, x.y, p1y);
            p2x = fmaf(w.z, x.x, p2x); p2y = fmaf(w.z, x.y, p2y);
            p3x = fmaf(w.w, x.x, p3x); p3y = fmaf(w.w, x.y, p3y);
        }
        float2* sc = (float2*)smem;              // [16][256] float2 = 32 KB
        sc[((uq << 2) + 0) * 256 + dp] = make_float2(p0x, p0y);
        sc[((uq << 2) + 1) * 256 + dp] = make_float2(p1x, p1y);
        sc[((uq << 2) + 2) * 256 + dp] = make_float2(p2x, p2y);
        sc[((uq << 2) + 3) * 256 + dp] = make_float2(p3x, p3y);
        __syncthreads();
        const int q = tid >> 8;                  // 0..3
        float2 s0 = sc[(0 + q) * 256 + dp];
        float2 s1 = sc[(4 + q) * 256 + dp];
        float2 s2 = sc[(8 + q) * 256 + dp];
        float2 s3 = sc[(12 + q) * 256 + dp];
        float2 o = make_float2(s0.x + s1.x + s2.x + s3.x,
                               s0.y + s1.y + s2.y + s3.y);
        *(float2*)&out[(size_t)((b << 7) + q0 + q) * 512 + (dp << 1)] = o;
    }
}

// ---------------------------------------------------------------------------
extern "C" void kernel_launch(void* const* d_in, const int* in_sizes, int n_in,
                              void* d_out, int out_size, void* d_ws, size_t ws_size,
                              hipStream_t stream) {
    const float* enc      = (const float*)d_in[0];
    const float* dec      = (const float*)d_in[1];
    const float* Wenc     = (const float*)d_in[2];
    const float* Wdec     = (const float*)d_in[3];
    const float* Wscore   = (const float*)d_in[4];
    const float* bias_enc = (const float*)d_in[5];
    const float* bias_dec = (const float*)d_in[6];
    // d_in[7] = bias_score: constant shift, cancelled by softmax.
    float* out = (float*)d_out;

    float* ws = (float*)d_ws;
    unsigned short* EH  = (unsigned short*)ws;             // 2 MB  (1M fp16)
    float* Gq4          = ws + 524288;                     // 2 MB  (512K fp32)
    unsigned short* WeT = (unsigned short*)(ws + 1048576); // 512 KB
    unsigned short* WdT = WeT + 262144;                    // 512 KB
    unsigned short* enc16 = WdT + 262144;                  // 2 MB
    unsigned short* dec16 = enc16 + 1048576;               // 1 MB   (total 8 MB)

    prep_w<<<224, 256, 0, stream>>>(Wenc, Wdec, enc, dec, WeT, WdT, enc16, dec16);
    proj_kernel<<<768, 128, 0, stream>>>(enc16, dec16, WeT, WdT,
                                         bias_enc, bias_dec, EH, Gq4);
    attend_kernel<<<256, 1024, 0, stream>>>(enc16, EH, Gq4, Wscore, out);
}